// Round 5
// baseline (182.909 us; speedup 1.0000x reference)
//
#include <hip/hip_runtime.h>
#include <hip/hip_bf16.h>
#include <math.h>

typedef __attribute__((ext_vector_type(8))) short bf16x8;
typedef __attribute__((ext_vector_type(4))) float f32x4;

#define NB 16
#define NM 16
#define NN 32
#define NT 80
#define TC 10   // timesteps per partial block
#define NP 8    // partial blocks per (b,m)

// ---- d_ws float layout ----
#define WS_WTS 0
#define WS_BASE 16
#define WS_BM_STRIDE 2112   // NP*256 feat partials + 64 scalars
#define WS_SC_OFF 2048

__device__ __forceinline__ unsigned pk2bf(float lo, float hi) {
  __hip_bfloat162 h = __float22bfloat162_rn(make_float2(lo, hi));  // v_cvt_pk_bf16_f32
  return *reinterpret_cast<unsigned*>(&h);
}
__device__ __forceinline__ short f2bf(float f) {
  unsigned u = __float_as_uint(f);
  u += 0x7fffu + ((u >> 16) & 1u);
  return (short)(u >> 16);
}

// ---------------- kernel 0: weights head (data-independent: enc_in = ones) ---
__global__ void weights_kernel(const float* __restrict__ wd_w1,
                               const float* __restrict__ wd_b1,
                               const float* __restrict__ wd_w2,
                               const float* __restrict__ wd_b2,
                               float* __restrict__ ws,
                               float* __restrict__ out) {
  __shared__ float sh[64];
  int j = threadIdx.x;
  if (j < 64) {
    float acc = wd_b1[j];
    for (int i = 0; i < 256; ++i) acc += wd_w1[i * 64 + j];
    sh[j] = acc > 0.f ? acc : expm1f(acc);  // elu
  }
  __syncthreads();
  if (j < 8) {
    float acc = wd_b2[j];
    for (int k = 0; k < 64; ++k) acc += sh[k] * wd_w2[k * 8 + j];
    float sp = log1pf(__expf(acc));  // softplus
    ws[WS_WTS + j] = sp;
    for (int b = 0; b < NB; ++b) out[NB * NM + b * 8 + j] = sp;  // weights output
  }
}

// ---------------- kernel 1: partial encoder/feature kernel ------------------
// grid = NB*NM*NP, 256 threads. Block (bm, p) handles t in [p*TC, p*TC+TC).
// 8 blocks/CU residency; 2-buf ping-pong; padded s_rel (conflict-free).
__global__ __launch_bounds__(256, 8) void score_partial(
    const float* __restrict__ ego_traj,      // [B][M][T][6]
    const float* __restrict__ agents_traj,   // [B][M][N][T][3]
    const float* __restrict__ agents_states, // [B][N][11]
    const float* __restrict__ enc_w1, const float* __restrict__ enc_b1,
    const float* __restrict__ enc_w2,
    float* __restrict__ ws)
{
  __shared__ float s_rel[5][TC][NN + 1];                // padded: bank=(i+n)%32
  __shared__ __align__(16) short s_hidden[2][NN * 64];  // 8 KB, 2 ping-pong bf16 tiles
  __shared__ float s_ego[TC][5];                        // ex,ey,eh,evx,evy
  __shared__ float s_acc[TC + 2];
  __shared__ float s_spd[TC], s_lat[TC], s_egos[TC];
  __shared__ float s_mask[NN];
  __shared__ float s_collpart[256];
  __shared__ float s_cw[32];

  const int bid = blockIdx.x;
  const int bm = bid >> 3;
  const int p = bid & 7;
  const int t0 = p * TC;
  const int b = bm >> 4;
  const int tid = threadIdx.x;
  const int lane = tid & 63;
  const int wv = tid >> 6;

  float* ws_bm = ws + WS_BASE + (size_t)bm * WS_BM_STRIDE;

  // ---- phase A: ego staging + agent mask ----
  if (tid < TC) {
    int i = tid;
    const float* e = ego_traj + ((size_t)bm * NT + (t0 + i)) * 6;
    float ex = e[0], ey = e[1], eh = e[2], spd = e[3], acc = e[4], cur = e[5];
    s_ego[i][0] = ex; s_ego[i][1] = ey; s_ego[i][2] = eh;
    s_ego[i][3] = spd * __cosf(eh);
    s_ego[i][4] = spd * __sinf(eh);
    s_spd[i] = spd;
    s_acc[i + 1] = acc;
    s_lat[i] = fabsf(spd * spd * cur);
    s_egos[i] = ex + ey + eh + spd + acc + cur;
  } else if (tid == TC) {
    int tp = (p == 0) ? 0 : (t0 - 1);
    s_acc[0] = ego_traj[((size_t)bm * NT + tp) * 6 + 4];
  } else if (tid >= 64 && tid < 64 + NN) {
    int n = tid - 64;
    const float* st = agents_states + ((size_t)b * NN + n) * 11;
    float s = 0.f;
    for (int i = 0; i < 11; ++i) s += st[i];
    s_mask[n] = (s != 0.f) ? 1.f : 0.f;
  }

  // prologue register loads (no LDS deps): enc_w1 cols, enc_w2 B-frags
  const int jq = tid & 15;        // j-quad: j0 = jq*4
  const int nh = tid >> 4;        // 0..15 -> handles n = nh and nh+16
  const int na = nh, nb_ = nh + 16;
  const int j0 = jq * 4;

  float w1r[5][4];
#pragma unroll
  for (int i = 0; i < 5; ++i)
#pragma unroll
    for (int jj = 0; jj < 4; ++jj)
      w1r[i][jj] = enc_w1[i * 64 + j0 + jj];

  bf16x8 Bf[4][2];  // enc_w2 B-frags: wave wv owns cols [wv*64, +64)
  {
    const int colb = lane & 15;
    const int krow = (lane >> 4) * 8;
#pragma unroll
    for (int ct = 0; ct < 4; ++ct) {
      int col = wv * 64 + ct * 16 + colb;
#pragma unroll
      for (int kt = 0; kt < 2; ++kt) {
#pragma unroll
        for (int j = 0; j < 8; ++j) {
          int k = kt * 32 + krow + j;
          Bf[ct][kt][j] = f2bf(enc_w2[k * 256 + col]);
        }
      }
    }
  }
  __syncthreads();  // barrier 1: s_ego/s_mask ready

  // ---- phase B: deduped rel features + coll (each (n,t) pair once) ----
  {
    float collacc = 0.f;
    const float* atraj = agents_traj + (size_t)bm * (NN * NT * 3);
#pragma unroll
    for (int k = 0; k < 2; ++k) {
      int pp = tid + k * 256;
      if (pp < NN * TC) {
        int n = pp / TC;
        int i = pp - n * TC;
        int tg = t0 + i;
        const float* bp = atraj + n * (NT * 3) + tg * 3;
        float ax = bp[0], ay = bp[1], ah = bp[2];
        float avx, avy;
        if (tg == 0) { avx = (bp[3] - ax) * 10.f; avy = (bp[4] - ay) * 10.f; }
        else         { avx = (ax - bp[-3]) * 10.f; avy = (ay - bp[-2]) * 10.f; }
        float ex = s_ego[i][0], ey = s_ego[i][1], eh = s_ego[i][2];
        float evx = s_ego[i][3], evy = s_ego[i][4];
        float m = s_mask[n];
        float ryr = ah - eh;
        float w = ryr - 6.283185307179586f * rintf(ryr * 0.15915494309189535f);
        float cy = __cosf(ryr), sy = __sinf(ryr);
        float dx = ax - ex, dy = ay - ey;
        s_rel[0][i][n] = dx * cy * m;
        s_rel[1][i][n] = dy * sy * m;
        s_rel[2][i][n] = w * m;
        s_rel[3][i][n] = (avx - evx) * cy * m;
        s_rel[4][i][n] = (avy - evy) * sy * m;
        collacc += __expf(-0.2f * (dx * dx + dy * dy)) * m;
      }
    }
    s_collpart[tid] = collacc;
  }

  // hard-feature partial sums on high tids (they have no rel pair: 320 < 251+256)
  if (tid >= 251) {
    int which = tid - 251;
    float s = 0.f;
    if (which == 0)      { for (int i = 0; i < TC; ++i) s += s_spd[i]; }
    else if (which == 1) { for (int i = 0; i < TC; ++i) s += fabsf(s_acc[i + 1]); }
    else if (which == 2) {
      for (int i = 0; i < TC; ++i) {
        int ia = (p == 0 && i == 0) ? 2 : (i + 1);
        s += fabsf((s_acc[ia] - s_acc[ia - 1]) * 10.f);
      }
    }
    else if (which == 3) { for (int i = 0; i < TC; ++i) s += s_lat[i]; }
    else                 { for (int i = 0; i < TC; ++i) s += s_egos[i]; }
    ws_bm[WS_SC_OFF + p * 8 + which] = s;
  }

  // baseB = mask * (agent_states[6:11] @ enc_w1[5:10]) + enc_b1, for both n's
  float baseA[4], baseBB[4];
#pragma unroll
  for (int half = 0; half < 2; ++half) {
    int n = half ? nb_ : na;
    const float* st = agents_states + ((size_t)b * NN + n) * 11 + 6;
    float m = s_mask[n];
    float a0 = st[0], a1 = st[1], a2 = st[2], a3 = st[3], a4 = st[4];
#pragma unroll
    for (int jj = 0; jj < 4; ++jj) {
      float acc = a0 * enc_w1[5 * 64 + j0 + jj] + a1 * enc_w1[6 * 64 + j0 + jj] +
                  a2 * enc_w1[7 * 64 + j0 + jj] + a3 * enc_w1[8 * 64 + j0 + jj] +
                  a4 * enc_w1[9 * 64 + j0 + jj];
      float v = m * acc + enc_b1[j0 + jj];
      if (half) baseBB[jj] = v; else baseA[jj] = v;
    }
  }

  // swizzled hidden-tile addresses (G4: byte ^= (row&7)<<4)
  const int wbyteA = (na * 128 + jq * 8) ^ ((na & 7) << 4);
  const int wbyteB = (nb_ * 128 + jq * 8) ^ ((nb_ & 7) << 4);
  int abyte[2][2];
  {
    int nbl = lane & 15;
    int kb = (lane >> 4) * 16;
#pragma unroll
    for (int rt = 0; rt < 2; ++rt) {
      int row = rt * 16 + nbl;
#pragma unroll
      for (int kt = 0; kt < 2; ++kt)
        abyte[rt][kt] = (row * 128 + kt * 64 + kb) ^ ((row & 7) << 4);
    }
  }

  // GEMM1 for local t=i -> swizzled bf16 tile in s_hidden[buf]
  auto compute_hidden = [&](int i, int buf) {
    float r0a = s_rel[0][i][na], r1a = s_rel[1][i][na], r2a = s_rel[2][i][na],
          r3a = s_rel[3][i][na], r4a = s_rel[4][i][na];
    float r0b = s_rel[0][i][nb_], r1b = s_rel[1][i][nb_], r2b = s_rel[2][i][nb_],
          r3b = s_rel[3][i][nb_], r4b = s_rel[4][i][nb_];
    float pa[4], pb[4];
#pragma unroll
    for (int jj = 0; jj < 4; ++jj) {
      pa[jj] = fmaxf(baseA[jj] + r0a * w1r[0][jj] + r1a * w1r[1][jj] +
                     r2a * w1r[2][jj] + r3a * w1r[3][jj] + r4a * w1r[4][jj], 0.f);
      pb[jj] = fmaxf(baseBB[jj] + r0b * w1r[0][jj] + r1b * w1r[1][jj] +
                     r2b * w1r[2][jj] + r3b * w1r[3][jj] + r4b * w1r[4][jj], 0.f);
    }
    char* hb = reinterpret_cast<char*>(&s_hidden[buf][0]);
    uint2 ua = {pk2bf(pa[0], pa[1]), pk2bf(pa[2], pa[3])};
    uint2 ub = {pk2bf(pb[0], pb[1]), pk2bf(pb[2], pb[3])};
    *reinterpret_cast<uint2*>(hb + wbyteA) = ua;
    *reinterpret_cast<uint2*>(hb + wbyteB) = ub;
  };

  float macc[4] = {0.f, 0.f, 0.f, 0.f};

  // MFMA + max-over-n + accumulate for one staged tile
  auto mfma_step = [&](int buf) {
    const char* hb = reinterpret_cast<const char*>(&s_hidden[buf][0]);
    bf16x8 a00 = *reinterpret_cast<const bf16x8*>(hb + abyte[0][0]);
    bf16x8 a01 = *reinterpret_cast<const bf16x8*>(hb + abyte[0][1]);
    bf16x8 a10 = *reinterpret_cast<const bf16x8*>(hb + abyte[1][0]);
    bf16x8 a11 = *reinterpret_cast<const bf16x8*>(hb + abyte[1][1]);
#pragma unroll
    for (int ct = 0; ct < 4; ++ct) {
      f32x4 c0 = {0.f, 0.f, 0.f, 0.f}, c1 = {0.f, 0.f, 0.f, 0.f};
      c0 = __builtin_amdgcn_mfma_f32_16x16x32_bf16(a00, Bf[ct][0], c0, 0, 0, 0);
      c0 = __builtin_amdgcn_mfma_f32_16x16x32_bf16(a01, Bf[ct][1], c0, 0, 0, 0);
      c1 = __builtin_amdgcn_mfma_f32_16x16x32_bf16(a10, Bf[ct][0], c1, 0, 0, 0);
      c1 = __builtin_amdgcn_mfma_f32_16x16x32_bf16(a11, Bf[ct][1], c1, 0, 0, 0);
      float v = fmaxf(fmaxf(fmaxf(c0[0], c1[0]), fmaxf(c0[1], c1[1])),
                      fmaxf(fmaxf(c0[2], c1[2]), fmaxf(c0[3], c1[3])));
      v = fmaxf(v, __shfl_xor(v, 16));
      v = fmaxf(v, __shfl_xor(v, 32));
      macc[ct] += v;
    }
  };

  __syncthreads();  // barrier 2: s_rel ready
  compute_hidden(0, 0);
  __syncthreads();  // barrier 3: buf 0 ready

  for (int i = 0; i < TC; ++i) {
    const int buf = i & 1;
    if (i + 1 < TC) compute_hidden(i + 1, buf ^ 1);  // write other buf
    mfma_step(buf);
    __syncthreads();
  }

  // ---- partial outputs ----
  if (lane < 16) {
#pragma unroll
    for (int ct = 0; ct < 4; ++ct)
      ws_bm[p * 256 + wv * 64 + ct * 16 + lane] = macc[ct];
  }
  if (tid < 32) {
    float s = 0.f;
#pragma unroll
    for (int k = 0; k < 8; ++k) s += s_collpart[tid + k * 32];
    s_cw[tid] = s;
  }
  __syncthreads();
  if (tid == 0) {
    float c = 0.f;
    for (int i = 0; i < 32; ++i) c += s_cw[i];
    ws_bm[WS_SC_OFF + p * 8 + 5] = c;
  }
}

// ---------------- kernel 2: combine + decoder + score -----------------------
__global__ void combine_kernel(const float* __restrict__ ws,
                               const float* __restrict__ enc_b2,
                               const float* __restrict__ dec_w1,
                               const float* __restrict__ dec_b1,
                               const float* __restrict__ dec_w2,
                               const float* __restrict__ dec_b2,
                               float* __restrict__ out_scores) {
  __shared__ float s_feat[256];
  __shared__ float s_dh[64];
  __shared__ float s_hard[4];
  __shared__ float s_inter[4];
  __shared__ float s_mc[2];  // egosum, coll
  const int bm = blockIdx.x;
  const int tid = threadIdx.x;  // 64 threads
  const float* wb = ws + WS_BASE + (size_t)bm * WS_BM_STRIDE;

  for (int c = tid; c < 256; c += 64) {
    float f = 0.f;
#pragma unroll
    for (int pp = 0; pp < NP; ++pp) f += wb[pp * 256 + c];
    s_feat[c] = f * (1.f / NT) + enc_b2[c];
  }
  const float* sc = wb + WS_SC_OFF;
  if (tid < 6) {
    float s = 0.f;
#pragma unroll
    for (int pp = 0; pp < NP; ++pp) s += sc[pp * 8 + tid];
    if (tid == 0) s_hard[0] = -fminf(fmaxf(s * (1.f / NT), 0.f), 15.f) * (1.f / 15.f);
    if (tid == 1) s_hard[1] = fminf(fmaxf(s * (1.f / NT), 0.f), 4.f) * 0.25f;
    if (tid == 2) s_hard[2] = fminf(fmaxf(s * (1.f / NT), 0.f), 6.f) * (1.f / 6.f);
    if (tid == 3) s_hard[3] = fminf(fmaxf(s * (1.f / NT), 0.f), 5.f) * 0.2f;
    if (tid == 4) s_mc[0] = s;
    if (tid == 5) s_mc[1] = s;
  }
  __syncthreads();

  {
    float a0 = 0.f, a1 = 0.f, a2 = 0.f, a3 = 0.f;
    for (int i = 0; i < 256; i += 4) {
      a0 += s_feat[i + 0] * dec_w1[(i + 0) * 64 + tid];
      a1 += s_feat[i + 1] * dec_w1[(i + 1) * 64 + tid];
      a2 += s_feat[i + 2] * dec_w1[(i + 2) * 64 + tid];
      a3 += s_feat[i + 3] * dec_w1[(i + 3) * 64 + tid];
    }
    float acc = dec_b1[tid] + ((a0 + a1) + (a2 + a3));
    s_dh[tid] = acc > 0.f ? acc : expm1f(acc);  // elu
  }
  __syncthreads();

  if (tid < 4) {
    float acc = dec_b2[tid];
    for (int k = 0; k < 64; ++k) acc += s_dh[k] * dec_w2[k * 4 + tid];
    s_inter[tid] = 1.f / (1.f + __expf(-acc));  // sigmoid
  }
  __syncthreads();

  if (tid == 0) {
    const float* wts = ws + WS_WTS;
    float scv = 0.f;
#pragma unroll
    for (int i = 0; i < 4; ++i) scv += s_hard[i] * wts[i];
#pragma unroll
    for (int i = 0; i < 4; ++i) scv += s_inter[i] * wts[4 + i];
    scv = -scv - 10.f * s_mc[1];
    if (s_mc[0] == 0.f) scv = -INFINITY;
    out_scores[bm] = scv;
  }
}

extern "C" void kernel_launch(void* const* d_in, const int* in_sizes, int n_in,
                              void* d_out, int out_size, void* d_ws, size_t ws_size,
                              hipStream_t stream) {
  const float* ego_traj      = (const float*)d_in[0];
  const float* agents_traj   = (const float*)d_in[2];
  const float* agents_states = (const float*)d_in[3];
  const float* enc_w1 = (const float*)d_in[4];
  const float* enc_b1 = (const float*)d_in[5];
  const float* enc_w2 = (const float*)d_in[6];
  const float* enc_b2 = (const float*)d_in[7];
  const float* dec_w1 = (const float*)d_in[8];
  const float* dec_b1 = (const float*)d_in[9];
  const float* dec_w2 = (const float*)d_in[10];
  const float* dec_b2 = (const float*)d_in[11];
  const float* wd_w1 = (const float*)d_in[12];
  const float* wd_b1 = (const float*)d_in[13];
  const float* wd_w2 = (const float*)d_in[14];
  const float* wd_b2 = (const float*)d_in[15];

  float* out = (float*)d_out;
  float* ws = (float*)d_ws;

  weights_kernel<<<1, 64, 0, stream>>>(wd_w1, wd_b1, wd_w2, wd_b2, ws, out);
  score_partial<<<NB * NM * NP, 256, 0, stream>>>(
      ego_traj, agents_traj, agents_states, enc_w1, enc_b1, enc_w2, ws);
  combine_kernel<<<NB * NM, 64, 0, stream>>>(
      ws, enc_b2, dec_w1, dec_b1, dec_w2, dec_b2, out);
}

// Round 6
// 56.281 us; speedup vs baseline: 3.2499x; 3.2499x over previous
//
#include <hip/hip_runtime.h>
#include <hip/hip_bf16.h>
#include <math.h>

typedef __attribute__((ext_vector_type(8))) short bf16x8;
typedef __attribute__((ext_vector_type(4))) float f32x4;

#define NB 16
#define NM 16
#define NN 32
#define NT 80
#define TC 10   // timesteps per partial block
#define NP 8    // partial blocks per (b,m)

// ---- d_ws float layout ----
#define WS_WTS 0
#define WS_BASE 16
#define WS_BM_STRIDE 2112   // NP*256 feat partials + 64 scalars
#define WS_SC_OFF 2048

__device__ __forceinline__ unsigned pk2bf(float lo, float hi) {
  __hip_bfloat162 h = __float22bfloat162_rn(make_float2(lo, hi));  // v_cvt_pk_bf16_f32
  return *reinterpret_cast<unsigned*>(&h);
}
__device__ __forceinline__ short f2bf(float f) {
  unsigned u = __float_as_uint(f);
  u += 0x7fffu + ((u >> 16) & 1u);
  return (short)(u >> 16);
}

// ---------------- kernel 0: weights head (data-independent: enc_in = ones) ---
__global__ void weights_kernel(const float* __restrict__ wd_w1,
                               const float* __restrict__ wd_b1,
                               const float* __restrict__ wd_w2,
                               const float* __restrict__ wd_b2,
                               float* __restrict__ ws,
                               float* __restrict__ out) {
  __shared__ float sh[64];
  int j = threadIdx.x;
  if (j < 64) {
    float acc = wd_b1[j];
    for (int i = 0; i < 256; ++i) acc += wd_w1[i * 64 + j];
    sh[j] = acc > 0.f ? acc : expm1f(acc);  // elu
  }
  __syncthreads();
  if (j < 8) {
    float acc = wd_b2[j];
    for (int k = 0; k < 64; ++k) acc += sh[k] * wd_w2[k * 8 + j];
    float sp = log1pf(__expf(acc));  // softplus
    ws[WS_WTS + j] = sp;
    for (int b = 0; b < NB; ++b) out[NB * NM + b * 8 + j] = sp;  // weights output
  }
}

// ---------------- kernel 1: partial encoder/feature kernel ------------------
// grid = NB*NM*NP, 256 threads. Block (bm, p) handles t in [p*TC, p*TC+TC).
// (256,4) bounds: R3-measured 64 VGPR no-spill; residency can still reach 8/CU.
__global__ __launch_bounds__(256, 4) void score_partial(
    const float* __restrict__ ego_traj,      // [B][M][T][6]
    const float* __restrict__ agents_traj,   // [B][M][N][T][3]
    const float* __restrict__ agents_states, // [B][N][11]
    const float* __restrict__ enc_w1, const float* __restrict__ enc_b1,
    const float* __restrict__ enc_w2,
    float* __restrict__ ws)
{
  __shared__ float s_rel[5][TC][NN + 1];                // padded: bank=(i+n)%32
  __shared__ __align__(16) short s_hidden[2][NN * 64];  // 8 KB, 2 ping-pong bf16 tiles
  __shared__ float s_ego[TC][5];                        // ex,ey,eh,evx,evy
  __shared__ float s_acc[TC + 2];
  __shared__ float s_spd[TC], s_lat[TC], s_egos[TC];
  __shared__ float s_mask[NN];
  __shared__ float s_collpart[256];
  __shared__ float s_cw[32];

  const int bid = blockIdx.x;
  const int bm = bid >> 3;
  const int p = bid & 7;
  const int t0 = p * TC;
  const int b = bm >> 4;
  const int tid = threadIdx.x;
  const int lane = tid & 63;
  const int wv = tid >> 6;

  float* ws_bm = ws + WS_BASE + (size_t)bm * WS_BM_STRIDE;

  // ---- phase A: ego staging + agent mask ----
  if (tid < TC) {
    int i = tid;
    const float* e = ego_traj + ((size_t)bm * NT + (t0 + i)) * 6;
    float ex = e[0], ey = e[1], eh = e[2], spd = e[3], acc = e[4], cur = e[5];
    s_ego[i][0] = ex; s_ego[i][1] = ey; s_ego[i][2] = eh;
    s_ego[i][3] = spd * __cosf(eh);
    s_ego[i][4] = spd * __sinf(eh);
    s_spd[i] = spd;
    s_acc[i + 1] = acc;
    s_lat[i] = fabsf(spd * spd * cur);
    s_egos[i] = ex + ey + eh + spd + acc + cur;
  } else if (tid == TC) {
    int tp = (p == 0) ? 0 : (t0 - 1);
    s_acc[0] = ego_traj[((size_t)bm * NT + tp) * 6 + 4];
  } else if (tid >= 64 && tid < 64 + NN) {
    int n = tid - 64;
    const float* st = agents_states + ((size_t)b * NN + n) * 11;
    float s = 0.f;
    for (int i = 0; i < 11; ++i) s += st[i];
    s_mask[n] = (s != 0.f) ? 1.f : 0.f;
  }

  // prologue register loads (no LDS deps): enc_w1 cols, enc_w2 B-frags
  const int jq = tid & 15;        // j-quad: j0 = jq*4
  const int nh = tid >> 4;        // 0..15 -> handles n = nh and nh+16
  const int na = nh, nb_ = nh + 16;
  const int j0 = jq * 4;

  float w1r[5][4];
#pragma unroll
  for (int i = 0; i < 5; ++i)
#pragma unroll
    for (int jj = 0; jj < 4; ++jj)
      w1r[i][jj] = enc_w1[i * 64 + j0 + jj];

  bf16x8 Bf[4][2];  // enc_w2 B-frags: wave wv owns cols [wv*64, +64)
  {
    const int colb = lane & 15;
    const int krow = (lane >> 4) * 8;
#pragma unroll
    for (int ct = 0; ct < 4; ++ct) {
      int col = wv * 64 + ct * 16 + colb;
#pragma unroll
      for (int kt = 0; kt < 2; ++kt) {
#pragma unroll
        for (int j = 0; j < 8; ++j) {
          int k = kt * 32 + krow + j;
          Bf[ct][kt][j] = f2bf(enc_w2[k * 256 + col]);
        }
      }
    }
  }
  __syncthreads();  // barrier 1: s_ego/s_mask ready

  // ---- phase B: deduped rel features + coll (each (n,t) pair once) ----
  {
    float collacc = 0.f;
    const float* atraj = agents_traj + (size_t)bm * (NN * NT * 3);
#pragma unroll
    for (int k = 0; k < 2; ++k) {
      int pp = tid + k * 256;
      if (pp < NN * TC) {
        int n = pp / TC;
        int i = pp - n * TC;
        int tg = t0 + i;
        const float* bp = atraj + n * (NT * 3) + tg * 3;
        float ax = bp[0], ay = bp[1], ah = bp[2];
        float avx, avy;
        if (tg == 0) { avx = (bp[3] - ax) * 10.f; avy = (bp[4] - ay) * 10.f; }
        else         { avx = (ax - bp[-3]) * 10.f; avy = (ay - bp[-2]) * 10.f; }
        float ex = s_ego[i][0], ey = s_ego[i][1], eh = s_ego[i][2];
        float evx = s_ego[i][3], evy = s_ego[i][4];
        float m = s_mask[n];
        float ryr = ah - eh;
        float w = ryr - 6.283185307179586f * rintf(ryr * 0.15915494309189535f);
        float cy = __cosf(ryr), sy = __sinf(ryr);
        float dx = ax - ex, dy = ay - ey;
        s_rel[0][i][n] = dx * cy * m;
        s_rel[1][i][n] = dy * sy * m;
        s_rel[2][i][n] = w * m;
        s_rel[3][i][n] = (avx - evx) * cy * m;
        s_rel[4][i][n] = (avy - evy) * sy * m;
        collacc += __expf(-0.2f * (dx * dx + dy * dy)) * m;
      }
    }
    s_collpart[tid] = collacc;
  }

  // hard-feature partial sums on high tids
  if (tid >= 251) {
    int which = tid - 251;
    float s = 0.f;
    if (which == 0)      { for (int i = 0; i < TC; ++i) s += s_spd[i]; }
    else if (which == 1) { for (int i = 0; i < TC; ++i) s += fabsf(s_acc[i + 1]); }
    else if (which == 2) {
      for (int i = 0; i < TC; ++i) {
        int ia = (p == 0 && i == 0) ? 2 : (i + 1);
        s += fabsf((s_acc[ia] - s_acc[ia - 1]) * 10.f);
      }
    }
    else if (which == 3) { for (int i = 0; i < TC; ++i) s += s_lat[i]; }
    else                 { for (int i = 0; i < TC; ++i) s += s_egos[i]; }
    ws_bm[WS_SC_OFF + p * 8 + which] = s;
  }

  // baseB = mask * (agent_states[6:11] @ enc_w1[5:10]) + enc_b1, for both n's
  float baseA[4], baseBB[4];
#pragma unroll
  for (int half = 0; half < 2; ++half) {
    int n = half ? nb_ : na;
    const float* st = agents_states + ((size_t)b * NN + n) * 11 + 6;
    float m = s_mask[n];
    float a0 = st[0], a1 = st[1], a2 = st[2], a3 = st[3], a4 = st[4];
#pragma unroll
    for (int jj = 0; jj < 4; ++jj) {
      float acc = a0 * enc_w1[5 * 64 + j0 + jj] + a1 * enc_w1[6 * 64 + j0 + jj] +
                  a2 * enc_w1[7 * 64 + j0 + jj] + a3 * enc_w1[8 * 64 + j0 + jj] +
                  a4 * enc_w1[9 * 64 + j0 + jj];
      float v = m * acc + enc_b1[j0 + jj];
      if (half) baseBB[jj] = v; else baseA[jj] = v;
    }
  }

  // swizzled hidden-tile addresses (G4: byte ^= (row&7)<<4)
  const int wbyteA = (na * 128 + jq * 8) ^ ((na & 7) << 4);
  const int wbyteB = (nb_ * 128 + jq * 8) ^ ((nb_ & 7) << 4);
  int abyte[2][2];
  {
    int nbl = lane & 15;
    int kb = (lane >> 4) * 16;
#pragma unroll
    for (int rt = 0; rt < 2; ++rt) {
      int row = rt * 16 + nbl;
#pragma unroll
      for (int kt = 0; kt < 2; ++kt)
        abyte[rt][kt] = (row * 128 + kt * 64 + kb) ^ ((row & 7) << 4);
    }
  }

  // GEMM1 for local t=i -> swizzled bf16 tile in s_hidden[buf]
  auto compute_hidden = [&](int i, int buf) {
    float r0a = s_rel[0][i][na], r1a = s_rel[1][i][na], r2a = s_rel[2][i][na],
          r3a = s_rel[3][i][na], r4a = s_rel[4][i][na];
    float r0b = s_rel[0][i][nb_], r1b = s_rel[1][i][nb_], r2b = s_rel[2][i][nb_],
          r3b = s_rel[3][i][nb_], r4b = s_rel[4][i][nb_];
    float pa[4], pb[4];
#pragma unroll
    for (int jj = 0; jj < 4; ++jj) {
      pa[jj] = fmaxf(baseA[jj] + r0a * w1r[0][jj] + r1a * w1r[1][jj] +
                     r2a * w1r[2][jj] + r3a * w1r[3][jj] + r4a * w1r[4][jj], 0.f);
      pb[jj] = fmaxf(baseBB[jj] + r0b * w1r[0][jj] + r1b * w1r[1][jj] +
                     r2b * w1r[2][jj] + r3b * w1r[3][jj] + r4b * w1r[4][jj], 0.f);
    }
    char* hb = reinterpret_cast<char*>(&s_hidden[buf][0]);
    uint2 ua = {pk2bf(pa[0], pa[1]), pk2bf(pa[2], pa[3])};
    uint2 ub = {pk2bf(pb[0], pb[1]), pk2bf(pb[2], pb[3])};
    *reinterpret_cast<uint2*>(hb + wbyteA) = ua;
    *reinterpret_cast<uint2*>(hb + wbyteB) = ub;
  };

  float macc[4] = {0.f, 0.f, 0.f, 0.f};

  // MFMA + max-over-n + accumulate for one staged tile
  auto mfma_step = [&](int buf) {
    const char* hb = reinterpret_cast<const char*>(&s_hidden[buf][0]);
    bf16x8 a00 = *reinterpret_cast<const bf16x8*>(hb + abyte[0][0]);
    bf16x8 a01 = *reinterpret_cast<const bf16x8*>(hb + abyte[0][1]);
    bf16x8 a10 = *reinterpret_cast<const bf16x8*>(hb + abyte[1][0]);
    bf16x8 a11 = *reinterpret_cast<const bf16x8*>(hb + abyte[1][1]);
#pragma unroll
    for (int ct = 0; ct < 4; ++ct) {
      f32x4 c0 = {0.f, 0.f, 0.f, 0.f}, c1 = {0.f, 0.f, 0.f, 0.f};
      c0 = __builtin_amdgcn_mfma_f32_16x16x32_bf16(a00, Bf[ct][0], c0, 0, 0, 0);
      c0 = __builtin_amdgcn_mfma_f32_16x16x32_bf16(a01, Bf[ct][1], c0, 0, 0, 0);
      c1 = __builtin_amdgcn_mfma_f32_16x16x32_bf16(a10, Bf[ct][0], c1, 0, 0, 0);
      c1 = __builtin_amdgcn_mfma_f32_16x16x32_bf16(a11, Bf[ct][1], c1, 0, 0, 0);
      float v = fmaxf(fmaxf(fmaxf(c0[0], c1[0]), fmaxf(c0[1], c1[1])),
                      fmaxf(fmaxf(c0[2], c1[2]), fmaxf(c0[3], c1[3])));
      v = fmaxf(v, __shfl_xor(v, 16));
      v = fmaxf(v, __shfl_xor(v, 32));
      macc[ct] += v;
    }
  };

  __syncthreads();  // barrier 2: s_rel ready
  compute_hidden(0, 0);
  __syncthreads();  // barrier 3: buf 0 ready

  for (int i = 0; i < TC; ++i) {
    const int buf = i & 1;
    if (i + 1 < TC) compute_hidden(i + 1, buf ^ 1);  // write other buf
    mfma_step(buf);
    __syncthreads();
  }

  // ---- partial outputs ----
  if (lane < 16) {
#pragma unroll
    for (int ct = 0; ct < 4; ++ct)
      ws_bm[p * 256 + wv * 64 + ct * 16 + lane] = macc[ct];
  }
  if (tid < 32) {
    float s = 0.f;
#pragma unroll
    for (int k = 0; k < 8; ++k) s += s_collpart[tid + k * 32];
    s_cw[tid] = s;
  }
  __syncthreads();
  if (tid == 0) {
    float c = 0.f;
    for (int i = 0; i < 32; ++i) c += s_cw[i];
    ws_bm[WS_SC_OFF + p * 8 + 5] = c;
  }
}

// ---------------- kernel 2: combine + decoder + score -----------------------
__global__ void combine_kernel(const float* __restrict__ ws,
                               const float* __restrict__ enc_b2,
                               const float* __restrict__ dec_w1,
                               const float* __restrict__ dec_b1,
                               const float* __restrict__ dec_w2,
                               const float* __restrict__ dec_b2,
                               float* __restrict__ out_scores) {
  __shared__ float s_feat[256];
  __shared__ float s_dh[64];
  __shared__ float s_hard[4];
  __shared__ float s_inter[4];
  __shared__ float s_mc[2];  // egosum, coll
  const int bm = blockIdx.x;
  const int tid = threadIdx.x;  // 64 threads
  const float* wb = ws + WS_BASE + (size_t)bm * WS_BM_STRIDE;

  for (int c = tid; c < 256; c += 64) {
    float f = 0.f;
#pragma unroll
    for (int pp = 0; pp < NP; ++pp) f += wb[pp * 256 + c];
    s_feat[c] = f * (1.f / NT) + enc_b2[c];
  }
  const float* sc = wb + WS_SC_OFF;
  if (tid < 6) {
    float s = 0.f;
#pragma unroll
    for (int pp = 0; pp < NP; ++pp) s += sc[pp * 8 + tid];
    if (tid == 0) s_hard[0] = -fminf(fmaxf(s * (1.f / NT), 0.f), 15.f) * (1.f / 15.f);
    if (tid == 1) s_hard[1] = fminf(fmaxf(s * (1.f / NT), 0.f), 4.f) * 0.25f;
    if (tid == 2) s_hard[2] = fminf(fmaxf(s * (1.f / NT), 0.f), 6.f) * (1.f / 6.f);
    if (tid == 3) s_hard[3] = fminf(fmaxf(s * (1.f / NT), 0.f), 5.f) * 0.2f;
    if (tid == 4) s_mc[0] = s;
    if (tid == 5) s_mc[1] = s;
  }
  __syncthreads();

  {
    float a0 = 0.f, a1 = 0.f, a2 = 0.f, a3 = 0.f;
    for (int i = 0; i < 256; i += 4) {
      a0 += s_feat[i + 0] * dec_w1[(i + 0) * 64 + tid];
      a1 += s_feat[i + 1] * dec_w1[(i + 1) * 64 + tid];
      a2 += s_feat[i + 2] * dec_w1[(i + 2) * 64 + tid];
      a3 += s_feat[i + 3] * dec_w1[(i + 3) * 64 + tid];
    }
    float acc = dec_b1[tid] + ((a0 + a1) + (a2 + a3));
    s_dh[tid] = acc > 0.f ? acc : expm1f(acc);  // elu
  }
  __syncthreads();

  if (tid < 4) {
    float acc = dec_b2[tid];
    for (int k = 0; k < 64; ++k) acc += s_dh[k] * dec_w2[k * 4 + tid];
    s_inter[tid] = 1.f / (1.f + __expf(-acc));  // sigmoid
  }
  __syncthreads();

  if (tid == 0) {
    const float* wts = ws + WS_WTS;
    float scv = 0.f;
#pragma unroll
    for (int i = 0; i < 4; ++i) scv += s_hard[i] * wts[i];
#pragma unroll
    for (int i = 0; i < 4; ++i) scv += s_inter[i] * wts[4 + i];
    scv = -scv - 10.f * s_mc[1];
    if (s_mc[0] == 0.f) scv = -INFINITY;
    out_scores[bm] = scv;
  }
}

extern "C" void kernel_launch(void* const* d_in, const int* in_sizes, int n_in,
                              void* d_out, int out_size, void* d_ws, size_t ws_size,
                              hipStream_t stream) {
  const float* ego_traj      = (const float*)d_in[0];
  const float* agents_traj   = (const float*)d_in[2];
  const float* agents_states = (const float*)d_in[3];
  const float* enc_w1 = (const float*)d_in[4];
  const float* enc_b1 = (const float*)d_in[5];
  const float* enc_w2 = (const float*)d_in[6];
  const float* enc_b2 = (const float*)d_in[7];
  const float* dec_w1 = (const float*)d_in[8];
  const float* dec_b1 = (const float*)d_in[9];
  const float* dec_w2 = (const float*)d_in[10];
  const float* dec_b2 = (const float*)d_in[11];
  const float* wd_w1 = (const float*)d_in[12];
  const float* wd_b1 = (const float*)d_in[13];
  const float* wd_w2 = (const float*)d_in[14];
  const float* wd_b2 = (const float*)d_in[15];

  float* out = (float*)d_out;
  float* ws = (float*)d_ws;

  weights_kernel<<<1, 64, 0, stream>>>(wd_w1, wd_b1, wd_w2, wd_b2, ws, out);
  score_partial<<<NB * NM * NP, 256, 0, stream>>>(
      ego_traj, agents_traj, agents_states, enc_w1, enc_b1, enc_w2, ws);
  combine_kernel<<<NB * NM, 64, 0, stream>>>(
      ws, enc_b2, dec_w1, dec_b1, dec_w2, dec_b2, out);
}

// Round 7
// 49.228 us; speedup vs baseline: 3.7155x; 1.1433x over previous
//
#include <hip/hip_runtime.h>
#include <hip/hip_bf16.h>
#include <math.h>

typedef __attribute__((ext_vector_type(8))) short bf16x8;
typedef __attribute__((ext_vector_type(4))) float f32x4;

#define NB 16
#define NM 16
#define NN 32
#define NT 80
#define TC 10   // timesteps per partial block
#define NP 8    // partial blocks per (b,m)

// ---- d_ws float layout ----
#define WS_WTS 0                 // 8 floats: softplus weights
#define WS_BF 16                 // 8192 floats: bf16 fragment table for enc_w2 (32 KB)
#define WS_BTBL 8208             // 32768 floats: baseB[b][n][64] (128 KB)
#define WS_BASE 40976            // partials, WS_BM_STRIDE per bm
#define WS_BM_STRIDE 2112        // NP*256 feat partials + 64 scalars
#define WS_SC_OFF 2048           // within-bm offset of scalar partials

__device__ __forceinline__ unsigned pk2bf(float lo, float hi) {
  __hip_bfloat162 h = __float22bfloat162_rn(make_float2(lo, hi));  // v_cvt_pk_bf16_f32
  return *reinterpret_cast<unsigned*>(&h);
}
__device__ __forceinline__ short f2bf(float f) {
  unsigned u = __float_as_uint(f);
  u += 0x7fffu + ((u >> 16) & 1u);
  return (short)(u >> 16);
}

// ---------------- kernel 0: prep — weight tables + weights head --------------
// blocks 0..15: baseB table for b = blockIdx. block 16: Bf frag table + wd head.
__global__ void prep_kernel(const float* __restrict__ agents_states,
                            const float* __restrict__ enc_w1,
                            const float* __restrict__ enc_b1,
                            const float* __restrict__ enc_w2,
                            const float* __restrict__ wd_w1,
                            const float* __restrict__ wd_b1,
                            const float* __restrict__ wd_w2,
                            const float* __restrict__ wd_b2,
                            float* __restrict__ ws,
                            float* __restrict__ out) {
  const int blk = blockIdx.x;
  const int tid = threadIdx.x;
  if (blk < NB) {
    // ---- baseB[b][n][j] = enc_b1[j] + mask_n * (states[6:11] @ enc_w1[5:10,j])
    __shared__ float smask[NN];
    if (tid < NN) {
      const float* st = agents_states + ((size_t)blk * NN + tid) * 11;
      float s = 0.f;
      for (int i = 0; i < 11; ++i) s += st[i];
      smask[tid] = (s != 0.f) ? 1.f : 0.f;
    }
    __syncthreads();
    for (int e = tid; e < NN * 64; e += 256) {
      int n = e >> 6, j = e & 63;
      const float* st = agents_states + ((size_t)blk * NN + n) * 11 + 6;
      float acc = st[0] * enc_w1[5 * 64 + j] + st[1] * enc_w1[6 * 64 + j] +
                  st[2] * enc_w1[7 * 64 + j] + st[3] * enc_w1[8 * 64 + j] +
                  st[4] * enc_w1[9 * 64 + j];
      ws[WS_BTBL + blk * (NN * 64) + e] = smask[n] * acc + enc_b1[j];
    }
  } else {
    // ---- weights head (enc_in = ones) ----
    __shared__ float sh[64];
    if (tid < 64) {
      float acc = wd_b1[tid];
      for (int i = 0; i < 256; ++i) acc += wd_w1[i * 64 + tid];
      sh[tid] = acc > 0.f ? acc : expm1f(acc);  // elu
    }
    __syncthreads();
    if (tid < 8) {
      float acc = wd_b2[tid];
      for (int k = 0; k < 64; ++k) acc += sh[k] * wd_w2[k * 8 + tid];
      float sp = log1pf(__expf(acc));  // softplus
      ws[WS_WTS + tid] = sp;
      for (int b = 0; b < NB; ++b) out[NB * NM + b * 8 + tid] = sp;
    }
    // ---- Bf fragment table: slot s=((wv*4+ct)*2+kt), entry per lane = bf16x8
    const int g = tid >> 6;      // 4 groups handle 8 slots each
    const int lane = tid & 63;
    bf16x8* bft = reinterpret_cast<bf16x8*>(ws + WS_BF);
#pragma unroll
    for (int q = 0; q < 8; ++q) {
      int s = g * 8 + q;
      int wv = s >> 3, ct = (s >> 1) & 3, kt = s & 1;
      int col = wv * 64 + ct * 16 + (lane & 15);
      int krow = (lane >> 4) * 8;
      bf16x8 v;
#pragma unroll
      for (int j = 0; j < 8; ++j)
        v[j] = f2bf(enc_w2[(kt * 32 + krow + j) * 256 + col]);
      bft[s * 64 + lane] = v;
    }
  }
}

// ---------------- kernel 1: partial encoder/feature kernel ------------------
// grid = NB*NM*NP, 256 threads. Block (bm, p) handles t in [p*TC, p*TC+TC).
__global__ __launch_bounds__(256, 4) void score_partial(
    const float* __restrict__ ego_traj,      // [B][M][T][6]
    const float* __restrict__ agents_traj,   // [B][M][N][T][3]
    const float* __restrict__ agents_states, // [B][N][11]
    const float* __restrict__ enc_w1,
    float* __restrict__ ws)
{
  __shared__ float s_rel[5][TC][NN + 1];                // padded: bank=(i+n)%32
  __shared__ __align__(16) short s_hidden[2][NN * 64];  // 8 KB, 2 ping-pong bf16 tiles
  __shared__ float s_ego[TC][5];                        // ex,ey,eh,evx,evy
  __shared__ float s_acc[TC + 2];
  __shared__ float s_spd[TC], s_lat[TC], s_egos[TC];
  __shared__ float s_mask[NN];
  __shared__ float s_collpart[256];
  __shared__ float s_cw[32];

  const int bid = blockIdx.x;
  const int bm = bid >> 3;
  const int p = bid & 7;
  const int t0 = p * TC;
  const int b = bm >> 4;
  const int tid = threadIdx.x;
  const int lane = tid & 63;
  const int wv = tid >> 6;

  float* ws_bm = ws + WS_BASE + (size_t)bm * WS_BM_STRIDE;

  // ---- phase A: ego staging + agent mask ----
  if (tid < TC) {
    int i = tid;
    const float* e = ego_traj + ((size_t)bm * NT + (t0 + i)) * 6;
    float ex = e[0], ey = e[1], eh = e[2], spd = e[3], acc = e[4], cur = e[5];
    s_ego[i][0] = ex; s_ego[i][1] = ey; s_ego[i][2] = eh;
    s_ego[i][3] = spd * __cosf(eh);
    s_ego[i][4] = spd * __sinf(eh);
    s_spd[i] = spd;
    s_acc[i + 1] = acc;
    s_lat[i] = fabsf(spd * spd * cur);
    s_egos[i] = ex + ey + eh + spd + acc + cur;
  } else if (tid == TC) {
    int tp = (p == 0) ? 0 : (t0 - 1);
    s_acc[0] = ego_traj[((size_t)bm * NT + tp) * 6 + 4];
  } else if (tid >= 64 && tid < 64 + NN) {
    int n = tid - 64;
    const float* st = agents_states + ((size_t)b * NN + n) * 11;
    float s = 0.f;
    for (int i = 0; i < 11; ++i) s += st[i];
    s_mask[n] = (s != 0.f) ? 1.f : 0.f;
  }

  // prologue register loads — all coalesced table reads now
  const int jq = tid & 15;        // j-quad: j0 = jq*4
  const int nh = tid >> 4;        // handles n = nh and nh+16
  const int na = nh, nb_ = nh + 16;
  const int j0 = jq * 4;

  float w1r[5][4];
#pragma unroll
  for (int i = 0; i < 5; ++i)
#pragma unroll
    for (int jj = 0; jj < 4; ++jj)
      w1r[i][jj] = enc_w1[i * 64 + j0 + jj];

  bf16x8 Bf[4][2];  // enc_w2 B-frags from table: 8 x 16B coalesced loads
  {
    const bf16x8* bft = reinterpret_cast<const bf16x8*>(ws + WS_BF);
#pragma unroll
    for (int ct = 0; ct < 4; ++ct)
#pragma unroll
      for (int kt = 0; kt < 2; ++kt) {
        int s = ((wv * 4 + ct) * 2 + kt);
        Bf[ct][kt] = bft[s * 64 + lane];
      }
  }

  // baseB from table: two float4 loads
  float baseA[4], baseBB[4];
  {
    const f32x4* bt = reinterpret_cast<const f32x4*>(ws + WS_BTBL + b * (NN * 64));
    f32x4 fa = bt[na * 16 + jq];
    f32x4 fb = bt[nb_ * 16 + jq];
#pragma unroll
    for (int jj = 0; jj < 4; ++jj) { baseA[jj] = fa[jj]; baseBB[jj] = fb[jj]; }
  }
  __syncthreads();  // barrier 1: s_ego/s_mask ready

  // ---- phase B: deduped rel features + coll (each (n,t) pair once) ----
  {
    float collacc = 0.f;
    const float* atraj = agents_traj + (size_t)bm * (NN * NT * 3);
#pragma unroll
    for (int k = 0; k < 2; ++k) {
      int pp = tid + k * 256;
      if (pp < NN * TC) {
        int n = pp / TC;
        int i = pp - n * TC;
        int tg = t0 + i;
        const float* bp = atraj + n * (NT * 3) + tg * 3;
        float ax = bp[0], ay = bp[1], ah = bp[2];
        float avx, avy;
        if (tg == 0) { avx = (bp[3] - ax) * 10.f; avy = (bp[4] - ay) * 10.f; }
        else         { avx = (ax - bp[-3]) * 10.f; avy = (ay - bp[-2]) * 10.f; }
        float ex = s_ego[i][0], ey = s_ego[i][1], eh = s_ego[i][2];
        float evx = s_ego[i][3], evy = s_ego[i][4];
        float m = s_mask[n];
        float ryr = ah - eh;
        float w = ryr - 6.283185307179586f * rintf(ryr * 0.15915494309189535f);
        float cy = __cosf(ryr), sy = __sinf(ryr);
        float dx = ax - ex, dy = ay - ey;
        s_rel[0][i][n] = dx * cy * m;
        s_rel[1][i][n] = dy * sy * m;
        s_rel[2][i][n] = w * m;
        s_rel[3][i][n] = (avx - evx) * cy * m;
        s_rel[4][i][n] = (avy - evy) * sy * m;
        collacc += __expf(-0.2f * (dx * dx + dy * dy)) * m;
      }
    }
    s_collpart[tid] = collacc;
  }

  // hard-feature partial sums on high tids
  if (tid >= 251) {
    int which = tid - 251;
    float s = 0.f;
    if (which == 0)      { for (int i = 0; i < TC; ++i) s += s_spd[i]; }
    else if (which == 1) { for (int i = 0; i < TC; ++i) s += fabsf(s_acc[i + 1]); }
    else if (which == 2) {
      for (int i = 0; i < TC; ++i) {
        int ia = (p == 0 && i == 0) ? 2 : (i + 1);
        s += fabsf((s_acc[ia] - s_acc[ia - 1]) * 10.f);
      }
    }
    else if (which == 3) { for (int i = 0; i < TC; ++i) s += s_lat[i]; }
    else                 { for (int i = 0; i < TC; ++i) s += s_egos[i]; }
    ws_bm[WS_SC_OFF + p * 8 + which] = s;
  }

  // swizzled hidden-tile addresses (G4: byte ^= (row&7)<<4)
  const int wbyteA = (na * 128 + jq * 8) ^ ((na & 7) << 4);
  const int wbyteB = (nb_ * 128 + jq * 8) ^ ((nb_ & 7) << 4);
  int abyte[2][2];
  {
    int nbl = lane & 15;
    int kb = (lane >> 4) * 16;
#pragma unroll
    for (int rt = 0; rt < 2; ++rt) {
      int row = rt * 16 + nbl;
#pragma unroll
      for (int kt = 0; kt < 2; ++kt)
        abyte[rt][kt] = (row * 128 + kt * 64 + kb) ^ ((row & 7) << 4);
    }
  }

  // GEMM1 for local t=i -> swizzled bf16 tile in s_hidden[buf]
  auto compute_hidden = [&](int i, int buf) {
    float r0a = s_rel[0][i][na], r1a = s_rel[1][i][na], r2a = s_rel[2][i][na],
          r3a = s_rel[3][i][na], r4a = s_rel[4][i][na];
    float r0b = s_rel[0][i][nb_], r1b = s_rel[1][i][nb_], r2b = s_rel[2][i][nb_],
          r3b = s_rel[3][i][nb_], r4b = s_rel[4][i][nb_];
    float pa[4], pb[4];
#pragma unroll
    for (int jj = 0; jj < 4; ++jj) {
      pa[jj] = fmaxf(baseA[jj] + r0a * w1r[0][jj] + r1a * w1r[1][jj] +
                     r2a * w1r[2][jj] + r3a * w1r[3][jj] + r4a * w1r[4][jj], 0.f);
      pb[jj] = fmaxf(baseBB[jj] + r0b * w1r[0][jj] + r1b * w1r[1][jj] +
                     r2b * w1r[2][jj] + r3b * w1r[3][jj] + r4b * w1r[4][jj], 0.f);
    }
    char* hb = reinterpret_cast<char*>(&s_hidden[buf][0]);
    uint2 ua = {pk2bf(pa[0], pa[1]), pk2bf(pa[2], pa[3])};
    uint2 ub = {pk2bf(pb[0], pb[1]), pk2bf(pb[2], pb[3])};
    *reinterpret_cast<uint2*>(hb + wbyteA) = ua;
    *reinterpret_cast<uint2*>(hb + wbyteB) = ub;
  };

  float macc[4] = {0.f, 0.f, 0.f, 0.f};

  auto mfma_step = [&](int buf) {
    const char* hb = reinterpret_cast<const char*>(&s_hidden[buf][0]);
    bf16x8 a00 = *reinterpret_cast<const bf16x8*>(hb + abyte[0][0]);
    bf16x8 a01 = *reinterpret_cast<const bf16x8*>(hb + abyte[0][1]);
    bf16x8 a10 = *reinterpret_cast<const bf16x8*>(hb + abyte[1][0]);
    bf16x8 a11 = *reinterpret_cast<const bf16x8*>(hb + abyte[1][1]);
#pragma unroll
    for (int ct = 0; ct < 4; ++ct) {
      f32x4 c0 = {0.f, 0.f, 0.f, 0.f}, c1 = {0.f, 0.f, 0.f, 0.f};
      c0 = __builtin_amdgcn_mfma_f32_16x16x32_bf16(a00, Bf[ct][0], c0, 0, 0, 0);
      c0 = __builtin_amdgcn_mfma_f32_16x16x32_bf16(a01, Bf[ct][1], c0, 0, 0, 0);
      c1 = __builtin_amdgcn_mfma_f32_16x16x32_bf16(a10, Bf[ct][0], c1, 0, 0, 0);
      c1 = __builtin_amdgcn_mfma_f32_16x16x32_bf16(a11, Bf[ct][1], c1, 0, 0, 0);
      float v = fmaxf(fmaxf(fmaxf(c0[0], c1[0]), fmaxf(c0[1], c1[1])),
                      fmaxf(fmaxf(c0[2], c1[2]), fmaxf(c0[3], c1[3])));
      v = fmaxf(v, __shfl_xor(v, 16));
      v = fmaxf(v, __shfl_xor(v, 32));
      macc[ct] += v;
    }
  };

  __syncthreads();  // barrier 2: s_rel ready
  compute_hidden(0, 0);
  __syncthreads();  // barrier 3: buf 0 ready

  for (int i = 0; i < TC; ++i) {
    const int buf = i & 1;
    if (i + 1 < TC) compute_hidden(i + 1, buf ^ 1);  // write other buf
    mfma_step(buf);
    __syncthreads();
  }

  // ---- partial outputs ----
  if (lane < 16) {
#pragma unroll
    for (int ct = 0; ct < 4; ++ct)
      ws_bm[p * 256 + wv * 64 + ct * 16 + lane] = macc[ct];
  }
  if (tid < 32) {
    float s = 0.f;
#pragma unroll
    for (int k = 0; k < 8; ++k) s += s_collpart[tid + k * 32];
    s_cw[tid] = s;
  }
  __syncthreads();
  if (tid == 0) {
    float c = 0.f;
    for (int i = 0; i < 32; ++i) c += s_cw[i];
    ws_bm[WS_SC_OFF + p * 8 + 5] = c;
  }
}

// ---------------- kernel 2: combine + decoder + score -----------------------
__global__ void combine_kernel(const float* __restrict__ ws,
                               const float* __restrict__ enc_b2,
                               const float* __restrict__ dec_w1,
                               const float* __restrict__ dec_b1,
                               const float* __restrict__ dec_w2,
                               const float* __restrict__ dec_b2,
                               float* __restrict__ out_scores) {
  __shared__ float s_feat[256];
  __shared__ float s_dh[64];
  __shared__ float s_hard[4];
  __shared__ float s_inter[4];
  __shared__ float s_mc[2];  // egosum, coll
  const int bm = blockIdx.x;
  const int tid = threadIdx.x;  // 64 threads
  const float* wb = ws + WS_BASE + (size_t)bm * WS_BM_STRIDE;

  for (int c = tid; c < 256; c += 64) {
    float f = 0.f;
#pragma unroll
    for (int pp = 0; pp < NP; ++pp) f += wb[pp * 256 + c];
    s_feat[c] = f * (1.f / NT) + enc_b2[c];
  }
  const float* sc = wb + WS_SC_OFF;
  if (tid < 6) {
    float s = 0.f;
#pragma unroll
    for (int pp = 0; pp < NP; ++pp) s += sc[pp * 8 + tid];
    if (tid == 0) s_hard[0] = -fminf(fmaxf(s * (1.f / NT), 0.f), 15.f) * (1.f / 15.f);
    if (tid == 1) s_hard[1] = fminf(fmaxf(s * (1.f / NT), 0.f), 4.f) * 0.25f;
    if (tid == 2) s_hard[2] = fminf(fmaxf(s * (1.f / NT), 0.f), 6.f) * (1.f / 6.f);
    if (tid == 3) s_hard[3] = fminf(fmaxf(s * (1.f / NT), 0.f), 5.f) * 0.2f;
    if (tid == 4) s_mc[0] = s;
    if (tid == 5) s_mc[1] = s;
  }
  __syncthreads();

  {
    float a0 = 0.f, a1 = 0.f, a2 = 0.f, a3 = 0.f;
    for (int i = 0; i < 256; i += 4) {
      a0 += s_feat[i + 0] * dec_w1[(i + 0) * 64 + tid];
      a1 += s_feat[i + 1] * dec_w1[(i + 1) * 64 + tid];
      a2 += s_feat[i + 2] * dec_w1[(i + 2) * 64 + tid];
      a3 += s_feat[i + 3] * dec_w1[(i + 3) * 64 + tid];
    }
    float acc = dec_b1[tid] + ((a0 + a1) + (a2 + a3));
    s_dh[tid] = acc > 0.f ? acc : expm1f(acc);  // elu
  }
  __syncthreads();

  if (tid < 4) {
    float acc = dec_b2[tid];
    for (int k = 0; k < 64; ++k) acc += s_dh[k] * dec_w2[k * 4 + tid];
    s_inter[tid] = 1.f / (1.f + __expf(-acc));  // sigmoid
  }
  __syncthreads();

  if (tid == 0) {
    const float* wts = ws + WS_WTS;
    float scv = 0.f;
#pragma unroll
    for (int i = 0; i < 4; ++i) scv += s_hard[i] * wts[i];
#pragma unroll
    for (int i = 0; i < 4; ++i) scv += s_inter[i] * wts[4 + i];
    scv = -scv - 10.f * s_mc[1];
    if (s_mc[0] == 0.f) scv = -INFINITY;
    out_scores[bm] = scv;
  }
}

extern "C" void kernel_launch(void* const* d_in, const int* in_sizes, int n_in,
                              void* d_out, int out_size, void* d_ws, size_t ws_size,
                              hipStream_t stream) {
  const float* ego_traj      = (const float*)d_in[0];
  const float* agents_traj   = (const float*)d_in[2];
  const float* agents_states = (const float*)d_in[3];
  const float* enc_w1 = (const float*)d_in[4];
  const float* enc_b1 = (const float*)d_in[5];
  const float* enc_w2 = (const float*)d_in[6];
  const float* enc_b2 = (const float*)d_in[7];
  const float* dec_w1 = (const float*)d_in[8];
  const float* dec_b1 = (const float*)d_in[9];
  const float* dec_w2 = (const float*)d_in[10];
  const float* dec_b2 = (const float*)d_in[11];
  const float* wd_w1 = (const float*)d_in[12];
  const float* wd_b1 = (const float*)d_in[13];
  const float* wd_w2 = (const float*)d_in[14];
  const float* wd_b2 = (const float*)d_in[15];

  float* out = (float*)d_out;
  float* ws = (float*)d_ws;

  prep_kernel<<<NB + 1, 256, 0, stream>>>(agents_states, enc_w1, enc_b1, enc_w2,
                                          wd_w1, wd_b1, wd_w2, wd_b2, ws, out);
  score_partial<<<NB * NM * NP, 256, 0, stream>>>(
      ego_traj, agents_traj, agents_states, enc_w1, ws);
  combine_kernel<<<NB * NM, 64, 0, stream>>>(
      ws, enc_b2, dec_w1, dec_b1, dec_w2, dec_b2, out);
}

// Round 9
// 45.964 us; speedup vs baseline: 3.9794x; 1.0710x over previous
//
#include <hip/hip_runtime.h>
#include <hip/hip_fp16.h>
#include <math.h>
#include <string.h>

typedef __attribute__((ext_vector_type(8))) short short8;
typedef __attribute__((ext_vector_type(8))) _Float16 f16x8;
typedef __attribute__((ext_vector_type(2))) _Float16 h2;
typedef __attribute__((ext_vector_type(4))) float f32x4;

#define NB 16
#define NM 16
#define NN 32
#define NT 80
#define TC 10   // timesteps per partial block
#define NP 8    // partial blocks per (b,m)

// ---- d_ws float-slot layout ----
#define WS_WTS 0                 // 8 floats: softplus weights
#define WS_BF 16                 // 8192 float-slots: f16 frag table enc_w2 (32 KB)
#define WS_BB 8208               // 16384 float-slots: baseB[b][n][32 h2] (64 KB)
#define WS_BASE 24592            // partials, WS_BM_STRIDE per bm
#define WS_BM_STRIDE 2112        // NP*256 feat partials + 64 scalars
#define WS_SC_OFF 2048           // within-bm offset of scalar partials

__device__ __forceinline__ short f2h(float f) {
  _Float16 h = (_Float16)f;
  short s; memcpy(&s, &h, 2); return s;
}
__device__ __forceinline__ unsigned h2bits(h2 h) {
  unsigned u; memcpy(&u, &h, 4); return u;
}

// ---------------- kernel 0: prep — f16 weight tables + weights head ----------
// blocks 0..15: baseB h2 table for b = blockIdx. block 16: Bf table + wd head.
__global__ void prep_kernel(const float* __restrict__ agents_states,
                            const float* __restrict__ enc_w1,
                            const float* __restrict__ enc_b1,
                            const float* __restrict__ enc_w2,
                            const float* __restrict__ wd_w1,
                            const float* __restrict__ wd_b1,
                            const float* __restrict__ wd_w2,
                            const float* __restrict__ wd_b2,
                            float* __restrict__ ws,
                            float* __restrict__ out) {
  const int blk = blockIdx.x;
  const int tid = threadIdx.x;
  if (blk < NB) {
    // baseB[b][n][j] = enc_b1[j] + mask_n * (states[6:11] @ enc_w1[5:10,j]) -> h2
    __shared__ float smask[NN];
    if (tid < NN) {
      const float* st = agents_states + ((size_t)blk * NN + tid) * 11;
      float s = 0.f;
      for (int i = 0; i < 11; ++i) s += st[i];
      smask[tid] = (s != 0.f) ? 1.f : 0.f;
    }
    __syncthreads();
    h2* bb = reinterpret_cast<h2*>(ws + WS_BB) + blk * (NN * 32);
    for (int e = tid; e < NN * 32; e += 256) {   // e = n*32 + jpair
      int n = e >> 5, jp = e & 31;
      const float* st = agents_states + ((size_t)blk * NN + n) * 11 + 6;
      float v[2];
#pragma unroll
      for (int hh = 0; hh < 2; ++hh) {
        int j = jp * 2 + hh;
        float acc = st[0] * enc_w1[5 * 64 + j] + st[1] * enc_w1[6 * 64 + j] +
                    st[2] * enc_w1[7 * 64 + j] + st[3] * enc_w1[8 * 64 + j] +
                    st[4] * enc_w1[9 * 64 + j];
        v[hh] = smask[n] * acc + enc_b1[j];
      }
      h2 r; r[0] = (_Float16)v[0]; r[1] = (_Float16)v[1];
      bb[e] = r;
    }
  } else {
    // ---- weights head (enc_in = ones) ----
    __shared__ float sh[64];
    if (tid < 64) {
      float acc = wd_b1[tid];
      for (int i = 0; i < 256; ++i) acc += wd_w1[i * 64 + tid];
      sh[tid] = acc > 0.f ? acc : expm1f(acc);  // elu
    }
    __syncthreads();
    if (tid < 8) {
      float acc = wd_b2[tid];
      for (int k = 0; k < 64; ++k) acc += sh[k] * wd_w2[k * 8 + tid];
      float sp = log1pf(__expf(acc));  // softplus
      ws[WS_WTS + tid] = sp;
      for (int b = 0; b < NB; ++b) out[NB * NM + b * 8 + tid] = sp;
    }
    // f16 Bf fragment table: slot s=((wv*4+ct)*2+kt), per-lane short8
    const int g = tid >> 6;
    const int lane = tid & 63;
    short8* bft = reinterpret_cast<short8*>(ws + WS_BF);
#pragma unroll
    for (int q = 0; q < 8; ++q) {
      int s = g * 8 + q;
      int wv = s >> 3, ct = (s >> 1) & 3, kt = s & 1;
      int col = wv * 64 + ct * 16 + (lane & 15);
      int krow = (lane >> 4) * 8;
      short8 v;
#pragma unroll
      for (int j = 0; j < 8; ++j)
        v[j] = f2h(enc_w2[(kt * 32 + krow + j) * 256 + col]);
      bft[s * 64 + lane] = v;
    }
  }
}

// ---------------- kernel 1: partial encoder/feature kernel ------------------
// grid = NB*NM*NP, 256 threads. Block (bm, p) handles t in [p*TC, p*TC+TC).
__global__ __launch_bounds__(256, 4) void score_partial(
    const float* __restrict__ ego_traj,      // [B][M][T][6]
    const float* __restrict__ agents_traj,   // [B][M][N][T][3]
    const float* __restrict__ agents_states, // [B][N][11]
    const float* __restrict__ enc_w1,        // [10][64]
    float* __restrict__ ws)
{
  __shared__ h2 s_rel[5][TC][NN + 1];                   // broadcast h2, padded
  __shared__ __align__(16) short s_hidden[2][NN * 64];  // 8 KB, 2 ping-pong f16 tiles
  __shared__ float s_ego[TC][5];
  __shared__ float s_acc[TC + 2];
  __shared__ float s_spd[TC], s_lat[TC], s_egos[TC];
  __shared__ float s_mask[NN];
  __shared__ float s_cw[4];

  const int bid = blockIdx.x;
  const int bm = bid >> 3;
  const int p = bid & 7;
  const int t0 = p * TC;
  const int b = bm >> 4;
  const int tid = threadIdx.x;
  const int lane = tid & 63;
  const int wv = tid >> 6;

  float* ws_bm = ws + WS_BASE + (size_t)bm * WS_BM_STRIDE;

  // ---- phase A: ego staging + agent mask ----
  if (tid < TC) {
    int i = tid;
    const float* e = ego_traj + ((size_t)bm * NT + (t0 + i)) * 6;
    float ex = e[0], ey = e[1], eh = e[2], spd = e[3], acc = e[4], cur = e[5];
    s_ego[i][0] = ex; s_ego[i][1] = ey; s_ego[i][2] = eh;
    s_ego[i][3] = spd * __cosf(eh);
    s_ego[i][4] = spd * __sinf(eh);
    s_spd[i] = spd;
    s_acc[i + 1] = acc;
    s_lat[i] = fabsf(spd * spd * cur);
    s_egos[i] = ex + ey + eh + spd + acc + cur;
  } else if (tid == TC) {
    int tp = (p == 0) ? 0 : (t0 - 1);
    s_acc[0] = ego_traj[((size_t)bm * NT + tp) * 6 + 4];
  } else if (tid >= 64 && tid < 64 + NN) {
    int n = tid - 64;
    const float* st = agents_states + ((size_t)b * NN + n) * 11;
    float s = 0.f;
    for (int i = 0; i < 11; ++i) s += st[i];
    s_mask[n] = (s != 0.f) ? 1.f : 0.f;
  }

  const int jq = tid & 15;        // j-quad: j0 = jq*4
  const int nh = tid >> 4;        // handles n = nh and nh+16
  const int na = nh, nb_ = nh + 16;
  const int j0 = jq * 4;

  f16x8 Bf[4][2];  // enc_w2 f16 B-frags from table
  {
    const f16x8* bft = reinterpret_cast<const f16x8*>(ws + WS_BF);
#pragma unroll
    for (int ct = 0; ct < 4; ++ct)
#pragma unroll
      for (int kt = 0; kt < 2; ++kt)
        Bf[ct][kt] = bft[((wv * 4 + ct) * 2 + kt) * 64 + lane];
  }

  // w1 as h2 pairs x 5 features (10 VGPR)
  h2 w1h[5][2];
#pragma unroll
  for (int f = 0; f < 5; ++f)
#pragma unroll
    for (int jp = 0; jp < 2; ++jp) {
      h2 r;
      r[0] = (_Float16)enc_w1[f * 64 + j0 + jp * 2];
      r[1] = (_Float16)enc_w1[f * 64 + j0 + jp * 2 + 1];
      w1h[f][jp] = r;
    }

  // baseB h2 pairs from table
  h2 baseA2[2], baseB2[2];
  {
    const h2* bb = reinterpret_cast<const h2*>(ws + WS_BB) + b * (NN * 32);
    baseA2[0] = bb[na * 32 + jq * 2];
    baseA2[1] = bb[na * 32 + jq * 2 + 1];
    baseB2[0] = bb[nb_ * 32 + jq * 2];
    baseB2[1] = bb[nb_ * 32 + jq * 2 + 1];
  }
  __syncthreads();  // barrier 1: s_ego/s_mask ready

  // ---- phase B: deduped rel features (h2 broadcast) + coll ----
  {
    float collacc = 0.f;
    const float* atraj = agents_traj + (size_t)bm * (NN * NT * 3);
#pragma unroll
    for (int k = 0; k < 2; ++k) {
      int pp = tid + k * 256;
      if (pp < NN * TC) {
        int n = pp / TC;
        int i = pp - n * TC;
        int tg = t0 + i;
        const float* bp = atraj + n * (NT * 3) + tg * 3;
        float ax = bp[0], ay = bp[1], ah = bp[2];
        float avx, avy;
        if (tg == 0) { avx = (bp[3] - ax) * 10.f; avy = (bp[4] - ay) * 10.f; }
        else         { avx = (ax - bp[-3]) * 10.f; avy = (ay - bp[-2]) * 10.f; }
        float ex = s_ego[i][0], ey = s_ego[i][1], eh = s_ego[i][2];
        float evx = s_ego[i][3], evy = s_ego[i][4];
        float m = s_mask[n];
        float ryr = ah - eh;
        float w = ryr - 6.283185307179586f * rintf(ryr * 0.15915494309189535f);
        float cy = __cosf(ryr), sy = __sinf(ryr);
        float dx = ax - ex, dy = ay - ey;
        float r0 = dx * cy * m, r1 = dy * sy * m, r2 = w * m;
        float r3 = (avx - evx) * cy * m, r4 = (avy - evy) * sy * m;
        h2 v0, v1, v2, v3, v4;
        v0[0] = v0[1] = (_Float16)r0;
        v1[0] = v1[1] = (_Float16)r1;
        v2[0] = v2[1] = (_Float16)r2;
        v3[0] = v3[1] = (_Float16)r3;
        v4[0] = v4[1] = (_Float16)r4;
        s_rel[0][i][n] = v0;
        s_rel[1][i][n] = v1;
        s_rel[2][i][n] = v2;
        s_rel[3][i][n] = v3;
        s_rel[4][i][n] = v4;
        collacc += __expf(-0.2f * (dx * dx + dy * dy)) * m;
      }
    }
#pragma unroll
    for (int off = 1; off < 64; off <<= 1) collacc += __shfl_xor(collacc, off);
    if (lane == 0) s_cw[wv] = collacc;
  }

  // hard-feature partial sums on high tids
  if (tid >= 251) {
    int which = tid - 251;
    float s = 0.f;
    if (which == 0)      { for (int i = 0; i < TC; ++i) s += s_spd[i]; }
    else if (which == 1) { for (int i = 0; i < TC; ++i) s += fabsf(s_acc[i + 1]); }
    else if (which == 2) {
      for (int i = 0; i < TC; ++i) {
        int ia = (p == 0 && i == 0) ? 2 : (i + 1);
        s += fabsf((s_acc[ia] - s_acc[ia - 1]) * 10.f);
      }
    }
    else if (which == 3) { for (int i = 0; i < TC; ++i) s += s_lat[i]; }
    else                 { for (int i = 0; i < TC; ++i) s += s_egos[i]; }
    ws_bm[WS_SC_OFF + p * 8 + which] = s;
  }

  // swizzled hidden-tile addresses (G4: byte ^= (row&7)<<4)
  const int wbyteA = (na * 128 + jq * 8) ^ ((na & 7) << 4);
  const int wbyteB = (nb_ * 128 + jq * 8) ^ ((nb_ & 7) << 4);
  int abyte[2][2];
  {
    int nbl = lane & 15;
    int kb = (lane >> 4) * 16;
#pragma unroll
    for (int rt = 0; rt < 2; ++rt) {
      int row = rt * 16 + nbl;
#pragma unroll
      for (int kt = 0; kt < 2; ++kt)
        abyte[rt][kt] = (row * 128 + kt * 64 + kb) ^ ((row & 7) << 4);
    }
  }

  h2 z2; z2[0] = z2[1] = (_Float16)0.f;

  // GEMM1 (packed f16) for local t=i -> f16 tile in s_hidden[buf]
  auto compute_hidden = [&](int i, int buf) {
    h2 ra0 = s_rel[0][i][na], ra1 = s_rel[1][i][na], ra2 = s_rel[2][i][na],
       ra3 = s_rel[3][i][na], ra4 = s_rel[4][i][na];
    h2 rb0 = s_rel[0][i][nb_], rb1 = s_rel[1][i][nb_], rb2 = s_rel[2][i][nb_],
       rb3 = s_rel[3][i][nb_], rb4 = s_rel[4][i][nb_];
    uint2 ua, ub;
#pragma unroll
    for (int jp = 0; jp < 2; ++jp) {
      h2 ha = baseA2[jp];
      ha = ra0 * w1h[0][jp] + ha;
      ha = ra1 * w1h[1][jp] + ha;
      ha = ra2 * w1h[2][jp] + ha;
      ha = ra3 * w1h[3][jp] + ha;
      ha = ra4 * w1h[4][jp] + ha;
      ha = __builtin_elementwise_max(ha, z2);
      h2 hb2 = baseB2[jp];
      hb2 = rb0 * w1h[0][jp] + hb2;
      hb2 = rb1 * w1h[1][jp] + hb2;
      hb2 = rb2 * w1h[2][jp] + hb2;
      hb2 = rb3 * w1h[3][jp] + hb2;
      hb2 = rb4 * w1h[4][jp] + hb2;
      hb2 = __builtin_elementwise_max(hb2, z2);
      if (jp == 0) { ua.x = h2bits(ha); ub.x = h2bits(hb2); }
      else         { ua.y = h2bits(ha); ub.y = h2bits(hb2); }
    }
    char* hb = reinterpret_cast<char*>(&s_hidden[buf][0]);
    *reinterpret_cast<uint2*>(hb + wbyteA) = ua;
    *reinterpret_cast<uint2*>(hb + wbyteB) = ub;
  };

  float macc[4] = {0.f, 0.f, 0.f, 0.f};

  auto mfma_step = [&](int buf) {
    const char* hb = reinterpret_cast<const char*>(&s_hidden[buf][0]);
    f16x8 a00 = *reinterpret_cast<const f16x8*>(hb + abyte[0][0]);
    f16x8 a01 = *reinterpret_cast<const f16x8*>(hb + abyte[0][1]);
    f16x8 a10 = *reinterpret_cast<const f16x8*>(hb + abyte[1][0]);
    f16x8 a11 = *reinterpret_cast<const f16x8*>(hb + abyte[1][1]);
#pragma unroll
    for (int ct = 0; ct < 4; ++ct) {
      f32x4 c0 = {0.f, 0.f, 0.f, 0.f}, c1 = {0.f, 0.f, 0.f, 0.f};
      c0 = __builtin_amdgcn_mfma_f32_16x16x32_f16(a00, Bf[ct][0], c0, 0, 0, 0);
      c0 = __builtin_amdgcn_mfma_f32_16x16x32_f16(a01, Bf[ct][1], c0, 0, 0, 0);
      c1 = __builtin_amdgcn_mfma_f32_16x16x32_f16(a10, Bf[ct][0], c1, 0, 0, 0);
      c1 = __builtin_amdgcn_mfma_f32_16x16x32_f16(a11, Bf[ct][1], c1, 0, 0, 0);
      float v = fmaxf(fmaxf(fmaxf(c0[0], c1[0]), fmaxf(c0[1], c1[1])),
                      fmaxf(fmaxf(c0[2], c1[2]), fmaxf(c0[3], c1[3])));
      v = fmaxf(v, __shfl_xor(v, 16));
      v = fmaxf(v, __shfl_xor(v, 32));
      macc[ct] += v;
    }
  };

  __syncthreads();  // barrier 2: s_rel ready
  compute_hidden(0, 0);
  __syncthreads();  // barrier 3: buf 0 ready

  for (int i = 0; i < TC; ++i) {
    const int buf = i & 1;
    if (i + 1 < TC) compute_hidden(i + 1, buf ^ 1);
    mfma_step(buf);
    __syncthreads();
  }

  // ---- partial outputs ----
  if (lane < 16) {
#pragma unroll
    for (int ct = 0; ct < 4; ++ct)
      ws_bm[p * 256 + wv * 64 + ct * 16 + lane] = macc[ct];
  }
  if (tid == 0)
    ws_bm[WS_SC_OFF + p * 8 + 5] = s_cw[0] + s_cw[1] + s_cw[2] + s_cw[3];
}

// ---------------- kernel 2: combine + decoder + score -----------------------
__global__ void combine_kernel(const float* __restrict__ ws,
                               const float* __restrict__ enc_b2,
                               const float* __restrict__ dec_w1,
                               const float* __restrict__ dec_b1,
                               const float* __restrict__ dec_w2,
                               const float* __restrict__ dec_b2,
                               float* __restrict__ out_scores) {
  __shared__ float s_feat[256];
  __shared__ float s_dh[64];
  __shared__ float s_hard[4];
  __shared__ float s_inter[4];
  __shared__ float s_mc[2];
  const int bm = blockIdx.x;
  const int tid = threadIdx.x;  // 64 threads
  const float* wb = ws + WS_BASE + (size_t)bm * WS_BM_STRIDE;

  for (int c = tid; c < 256; c += 64) {
    float f = 0.f;
#pragma unroll
    for (int pp = 0; pp < NP; ++pp) f += wb[pp * 256 + c];
    s_feat[c] = f * (1.f / NT) + enc_b2[c];
  }
  const float* sc = wb + WS_SC_OFF;
  if (tid < 6) {
    float s = 0.f;
#pragma unroll
    for (int pp = 0; pp < NP; ++pp) s += sc[pp * 8 + tid];
    if (tid == 0) s_hard[0] = -fminf(fmaxf(s * (1.f / NT), 0.f), 15.f) * (1.f / 15.f);
    if (tid == 1) s_hard[1] = fminf(fmaxf(s * (1.f / NT), 0.f), 4.f) * 0.25f;
    if (tid == 2) s_hard[2] = fminf(fmaxf(s * (1.f / NT), 0.f), 6.f) * (1.f / 6.f);
    if (tid == 3) s_hard[3] = fminf(fmaxf(s * (1.f / NT), 0.f), 5.f) * 0.2f;
    if (tid == 4) s_mc[0] = s;
    if (tid == 5) s_mc[1] = s;
  }
  __syncthreads();

  {
    float a0 = 0.f, a1 = 0.f, a2 = 0.f, a3 = 0.f;
    for (int i = 0; i < 256; i += 4) {
      a0 += s_feat[i + 0] * dec_w1[(i + 0) * 64 + tid];
      a1 += s_feat[i + 1] * dec_w1[(i + 1) * 64 + tid];
      a2 += s_feat[i + 2] * dec_w1[(i + 2) * 64 + tid];
      a3 += s_feat[i + 3] * dec_w1[(i + 3) * 64 + tid];
    }
    float acc = dec_b1[tid] + ((a0 + a1) + (a2 + a3));
    s_dh[tid] = acc > 0.f ? acc : expm1f(acc);  // elu
  }
  __syncthreads();

  if (tid < 4) {
    float acc = dec_b2[tid];
    for (int k = 0; k < 64; ++k) acc += s_dh[k] * dec_w2[k * 4 + tid];
    s_inter[tid] = 1.f / (1.f + __expf(-acc));  // sigmoid
  }
  __syncthreads();

  if (tid == 0) {
    const float* wts = ws + WS_WTS;
    float scv = 0.f;
#pragma unroll
    for (int i = 0; i < 4; ++i) scv += s_hard[i] * wts[i];
#pragma unroll
    for (int i = 0; i < 4; ++i) scv += s_inter[i] * wts[4 + i];
    scv = -scv - 10.f * s_mc[1];
    if (s_mc[0] == 0.f) scv = -INFINITY;
    out_scores[bm] = scv;
  }
}

extern "C" void kernel_launch(void* const* d_in, const int* in_sizes, int n_in,
                              void* d_out, int out_size, void* d_ws, size_t ws_size,
                              hipStream_t stream) {
  const float* ego_traj      = (const float*)d_in[0];
  const float* agents_traj   = (const float*)d_in[2];
  const float* agents_states = (const float*)d_in[3];
  const float* enc_w1 = (const float*)d_in[4];
  const float* enc_b1 = (const float*)d_in[5];
  const float* enc_w2 = (const float*)d_in[6];
  const float* enc_b2 = (const float*)d_in[7];
  const float* dec_w1 = (const float*)d_in[8];
  const float* dec_b1 = (const float*)d_in[9];
  const float* dec_w2 = (const float*)d_in[10];
  const float* dec_b2 = (const float*)d_in[11];
  const float* wd_w1 = (const float*)d_in[12];
  const float* wd_b1 = (const float*)d_in[13];
  const float* wd_w2 = (const float*)d_in[14];
  const float* wd_b2 = (const float*)d_in[15];

  float* out = (float*)d_out;
  float* ws = (float*)d_ws;

  prep_kernel<<<NB + 1, 256, 0, stream>>>(agents_states, enc_w1, enc_b1, enc_w2,
                                          wd_w1, wd_b1, wd_w2, wd_b2, ws, out);
  score_partial<<<NB * NM * NP, 256, 0, stream>>>(
      ego_traj, agents_traj, agents_states, enc_w1, ws);
  combine_kernel<<<NB * NM, 64, 0, stream>>>(
      ws, enc_b2, dec_w1, dec_b1, dec_w2, dec_b2, out);
}